// Round 10
// baseline (277.627 us; speedup 1.0000x reference)
//
#include <hip/hip_runtime.h>
#include <hip/hip_bf16.h>

typedef unsigned short ushort_t;
typedef short bf16x8 __attribute__((ext_vector_type(8)));
typedef ushort_t u16x8 __attribute__((ext_vector_type(8)));
typedef ushort_t u16x4 __attribute__((ext_vector_type(4)));
typedef float f32x4 __attribute__((ext_vector_type(4)));

#define DEV static __device__ __forceinline__

DEV float bf2f(ushort_t u) { unsigned v = ((unsigned)u) << 16; float f; __builtin_memcpy(&f, &v, 4); return f; }
DEV short f2bf(float x) { __hip_bfloat16 h = __float2bfloat16(x); short s; __builtin_memcpy(&s, &h, 2); return s; }
DEV float sigm(float x) { return 1.0f / (1.0f + __expf(-x)); }

DEV bf16x8 cvt8(float4 a0, float4 a1) {
    bf16x8 t;
    t[0] = f2bf(a0.x); t[1] = f2bf(a0.y); t[2] = f2bf(a0.z); t[3] = f2bf(a0.w);
    t[4] = f2bf(a1.x); t[5] = f2bf(a1.y); t[6] = f2bf(a1.z); t[7] = f2bf(a1.w);
    return t;
}
DEV bf16x8 ld8f(const float* __restrict__ p) {
    return cvt8(*reinterpret_cast<const float4*>(p), *reinterpret_cast<const float4*>(p + 4));
}

// ---------------- K0: fp32 -> bf16 for W1, Wv only
__global__ void k_cvtW(const float* __restrict__ W1, const float* __restrict__ Wv,
                       ushort_t* __restrict__ Wcat) {
    int i = blockIdx.x * 256 + threadIdx.x;  // 16384 threads, 8 elems each
    const float* src = (i < 8192) ? (W1 + (long)i * 8) : (Wv + (long)(i - 8192) * 8);
    const float4* p = reinterpret_cast<const float4*>(src);
    *reinterpret_cast<bf16x8*>(Wcat + (long)i * 8) = cvt8(p[0], p[1]);
}

// ---------------- K1: fused fv+feat, role-split for TLP. 1024 blocks.
// even bid (role 0): Ff = gelu(hidden@W1^T+b1) -> feat chain for 16 rows.
// odd bid  (role 1): VbT = (hidden@Wv^T)^T bf16 for the same 16 rows.
// Per wave: ONE acc chain (16 output cols), 4 blocks/CU -> 16 waves/CU.
__global__ __launch_bounds__(256) void k_fvfeat(const float* __restrict__ hidden,
        const ushort_t* __restrict__ Wcat, const float* __restrict__ b1,
        const float* __restrict__ W2, const float* __restrict__ b2,
        const float* __restrict__ Wq, const float* __restrict__ Wk,
        const float* __restrict__ Wc, const float* __restrict__ bc,
        ushort_t* __restrict__ Qb, ushort_t* __restrict__ Kb,
        ushort_t* __restrict__ VbT, float* __restrict__ charge0) {
    __shared__ float w2L[28 * 65], wqL[64 * 29], wkL[64 * 29], wcL[28], b2L[28];
    __shared__ float fLDS[16][65], featL[4][28];
    int tid = threadIdx.x;
    int role = blockIdx.x & 1;
    int m0 = (blockIdx.x >> 1) * 16;
    if (role == 0) {
        for (int i = tid; i < 28 * 64; i += 256) w2L[(i >> 6) * 65 + (i & 63)] = W2[i];
        for (int i = tid; i < 64 * 28; i += 256) {
            int r = i / 28, c = i - r * 28;
            wqL[r * 29 + c] = Wq[i];
            wkL[r * 29 + c] = Wk[i];
        }
        if (tid < 28) { wcL[tid] = Wc[tid]; b2L[tid] = b2[tid]; }
    }

    int wave = tid >> 6, lane = tid & 63, l16 = lane & 15, quad = lane >> 4;
    int brow_off = (role == 0) ? 0 : 64;   // Wcat rows 0-63 = W1, 64-127 = Wv
    f32x4 acc = {};
    const float* arow = hidden + (long)(m0 + l16) * 1024;
    const ushort_t* brow = Wcat + (long)(brow_off + wave * 16 + l16) * 1024;
    for (int kc = 0; kc < 1024; kc += 128) {
#pragma unroll
        for (int u = 0; u < 4; u++) {
            int ko = kc + u * 32 + quad * 8;
            bf16x8 a = ld8f(arow + ko);
            bf16x8 bfr = *reinterpret_cast<const bf16x8*>(brow + ko);
            acc = __builtin_amdgcn_mfma_f32_16x16x32_bf16(a, bfr, acc, 0, 0, 0);
        }
    }
    if (role == 1) {
#pragma unroll
        for (int rr = 0; rr < 4; rr++)
            VbT[(long)(wave * 16 + l16) * 8192 + (m0 + quad * 4 + rr)] =
                (ushort_t)f2bf(acc[rr]);
        return;
    }
    {
        float bv = b1[wave * 16 + l16];
#pragma unroll
        for (int rr = 0; rr < 4; rr++) {
            float x = acc[rr] + bv;
            fLDS[quad * 4 + rr][wave * 16 + l16] =
                0.5f * x * (1.0f + erff(x * 0.70710678118654752f));
        }
    }
    __syncthreads();
    float bcv = bc[0];
    for (int it = 0; it < 4; it++) {
        int rowl = it * 4 + wave;
        int row = m0 + rowl;
        if (lane < 28) {
            float s = b2L[lane];
#pragma unroll
            for (int j = 0; j < 64; j++) s += fLDS[rowl][j] * w2L[lane * 65 + j];
            featL[wave][lane] = sigm(s);
        }
        __syncthreads();
        float q = 0.f, k = 0.f;
#pragma unroll
        for (int i = 0; i < 28; i++) {
            float fv = featL[wave][i];
            q += fv * wqL[lane * 29 + i];
            k += fv * wkL[lane * 29 + i];
        }
        Qb[row * 64 + lane] = (ushort_t)f2bf(q * 0.125f);  // fold 1/sqrt(64)
        Kb[row * 64 + lane] = (ushort_t)f2bf(k);
        if (lane == 0) {
            float c = bcv;
#pragma unroll
            for (int i = 0; i < 28; i++) c += featL[wave][i] * wcL[i];
            charge0[row] = sigm(c);
        }
        __syncthreads();
    }
}

DEV void tri_decode(int r, int& ti, int& tj) {
    int t = (int)((sqrtf(8.f * (float)r + 1.f) - 1.f) * 0.5f);
    while ((t + 1) * (t + 2) / 2 <= r) t++;
    while (t * (t + 1) / 2 > r) t--;
    ti = t;
    tj = r - t * (t + 1) / 2;
}

// ---------------- K2: compat = (Q/8)·K, causal tiles split into 64-row halves.
// 1088 blocks; wave owns 16 rows (1 A-frag, 8 B-frags) -> 4.25 blocks/CU.
__global__ __launch_bounds__(256) void k_compat(const ushort_t* __restrict__ Qb,
                                                const ushort_t* __restrict__ Kb,
                                                ushort_t* __restrict__ compat) {
    int bid = blockIdx.x;
    int bid2 = bid >> 1, half = bid & 1;
    int b = bid2 / 136, r = bid2 % 136, ti, tj;
    tri_decode(r, ti, tj);
    int wave = threadIdx.x >> 6, lane = threadIdx.x & 63;
    int l16 = lane & 15, quad = lane >> 4;
    int rbase = b * 2048 + ti * 128 + half * 64 + wave * 16;
    int cbase = b * 2048 + tj * 128;
    f32x4 acc[8] = {};
#pragma unroll
    for (int kc = 0; kc < 64; kc += 32) {
        int ko = kc + quad * 8;
        bf16x8 af = *reinterpret_cast<const bf16x8*>(Qb + (long)(rbase + l16) * 64 + ko);
        bf16x8 bf[8];
#pragma unroll
        for (int f = 0; f < 8; f++)
            bf[f] = *reinterpret_cast<const bf16x8*>(Kb + (long)(cbase + f * 16 + l16) * 64 + ko);
#pragma unroll
        for (int j = 0; j < 8; j++)
            acc[j] = __builtin_amdgcn_mfma_f32_16x16x32_bf16(af, bf[j], acc[j], 0, 0, 0);
    }
    int colt = tj * 128;
#pragma unroll
    for (int j = 0; j < 8; j++)
#pragma unroll
        for (int rr = 0; rr < 4; rr++) {
            long rowg = rbase + quad * 4 + rr;
            int col = colt + j * 16 + l16;
            compat[rowg * 2048 + col] = (ushort_t)f2bf(acc[j][rr]);
        }
}

// ---------------- K3: single-pass strip kernel, iteration T.
// 1024 blocks = 4 batches x 256 pairs {A rows [4p,4p+4), B rows [2044-4p,2048-4p)}.
// Block-uniform guards skip fully-masked spans; zero-init arrays keep partials exact.
template <int T>
__global__ __launch_bounds__(256, 2) void k_strip(const ushort_t* __restrict__ compat,
        const float4* __restrict__ charges4, const float* __restrict__ stepp,
        float* __restrict__ Rpart) {
    __shared__ float chR[4][8];   // [comp][row: 0-3 A, 4-7 B]
    __shared__ float red[4][8], Li[8];
    int bid = blockIdx.x, tid = threadIdx.x;
    int b = bid >> 8, pi = bid & 255;
    int r0A = pi * 4, r0B = 2044 - pi * 4;
    float step = stepp[0];
    if (T > 0 && tid < 8) {
        int row = (tid < 4) ? (r0A + tid) : (r0B + tid - 4);
        float4 c4 = charges4[b * 2048 + row];
        chR[0][tid] = step * c4.x;
        if (T > 1) chR[1][tid] = step * c4.y;
        if (T > 2) chR[2][tid] = step * c4.z;
        if (T > 3) chR[3][tid] = step * c4.w;
    }
    __syncthreads();
    int w = tid >> 6, lane = tid & 63;
    int c0 = tid * 4;
    const ushort_t* base = compat + (long)(b * 2048) * 2048;

    float pA[4][4] = {}, pB0[4][4] = {}, pB1[4][4] = {};
    float SA[4] = {}, SB[4] = {};

    // ---- chunk 0: cols [c0, c0+4) in [0,1024)
    {
        float cx[4] = {}, cy[4] = {}, cz[4] = {}, cw[4] = {};
        if (T > 0) {
#pragma unroll
            for (int k = 0; k < 4; k++) {
                float4 c = charges4[b * 2048 + c0 + k];
                cx[k] = c.x;
                if (T > 1) cy[k] = c.y;
                if (T > 2) cz[k] = c.z;
                if (T > 3) cw[k] = c.w;
            }
        }
        if (c0 <= r0A + 3) {   // skip fully-masked A spans
#pragma unroll
            for (int rr = 0; rr < 4; rr++) {
                u16x4 v = *reinterpret_cast<const u16x4*>(base + (long)(r0A + rr) * 2048 + c0);
#pragma unroll
                for (int k = 0; k < 4; k++) {
                    float sg = 1.f;
                    if (T > 0) sg += chR[0][rr] * cx[k];
                    if (T > 1) sg += chR[1][rr] * cy[k];
                    if (T > 2) sg += chR[2][rr] * cz[k];
                    if (T > 3) sg += chR[3][rr] * cw[k];
                    float p = (c0 + k <= r0A + rr) ? __expf(bf2f(v[k]) * sg) : 0.f;
                    pA[rr][k] = p;
                    SA[rr] += p;
                }
            }
        }
#pragma unroll
        for (int rr = 0; rr < 4; rr++) {
            u16x4 v = *reinterpret_cast<const u16x4*>(base + (long)(r0B + rr) * 2048 + c0);
#pragma unroll
            for (int k = 0; k < 4; k++) {
                float sg = 1.f;
                if (T > 0) sg += chR[0][4 + rr] * cx[k];
                if (T > 1) sg += chR[1][4 + rr] * cy[k];
                if (T > 2) sg += chR[2][4 + rr] * cz[k];
                if (T > 3) sg += chR[3][4 + rr] * cw[k];
                float p = __expf(bf2f(v[k]) * sg);   // col<1024 <= r0B always
                pB0[rr][k] = p;
                SB[rr] += p;
            }
        }
    }
    // ---- chunk 1: cols 1024+[c0, c0+4), B rows only (masked, guarded)
    if (1024 + c0 <= r0B + 3) {
        float cx[4] = {}, cy[4] = {}, cz[4] = {}, cw[4] = {};
        if (T > 0) {
#pragma unroll
            for (int k = 0; k < 4; k++) {
                float4 c = charges4[b * 2048 + 1024 + c0 + k];
                cx[k] = c.x;
                if (T > 1) cy[k] = c.y;
                if (T > 2) cz[k] = c.z;
                if (T > 3) cw[k] = c.w;
            }
        }
#pragma unroll
        for (int rr = 0; rr < 4; rr++) {
            u16x4 v = *reinterpret_cast<const u16x4*>(base + (long)(r0B + rr) * 2048 + 1024 + c0);
#pragma unroll
            for (int k = 0; k < 4; k++) {
                float sg = 1.f;
                if (T > 0) sg += chR[0][4 + rr] * cx[k];
                if (T > 1) sg += chR[1][4 + rr] * cy[k];
                if (T > 2) sg += chR[2][4 + rr] * cz[k];
                if (T > 3) sg += chR[3][4 + rr] * cw[k];
                float p = (1024 + c0 + k <= r0B + rr) ? __expf(bf2f(v[k]) * sg) : 0.f;
                pB1[rr][k] = p;
                SB[rr] += p;
            }
        }
    }
    // ---- reduce row sums -> Li[8]
#pragma unroll
    for (int rr = 0; rr < 4; rr++) {
        float s = SA[rr];
        s += __shfl_xor(s, 1); s += __shfl_xor(s, 2); s += __shfl_xor(s, 4);
        s += __shfl_xor(s, 8); s += __shfl_xor(s, 16); s += __shfl_xor(s, 32);
        if (lane == 0) red[w][rr] = s;
        float t = SB[rr];
        t += __shfl_xor(t, 1); t += __shfl_xor(t, 2); t += __shfl_xor(t, 4);
        t += __shfl_xor(t, 8); t += __shfl_xor(t, 16); t += __shfl_xor(t, 32);
        if (lane == 0) red[w][4 + rr] = t;
    }
    __syncthreads();
    if (tid < 8) Li[tid] = 1.f / fmaxf(red[0][tid] + red[1][tid] + red[2][tid] + red[3][tid], 1e-30f);
    __syncthreads();
    float liA0 = Li[0], liA1 = Li[1], liA2 = Li[2], liA3 = Li[3];
    float liB0 = Li[4], liB1 = Li[5], liB2 = Li[6], liB3 = Li[7];
    float4 o0, o1;
    float* po0 = (float*)&o0;
    float* po1 = (float*)&o1;
#pragma unroll
    for (int k = 0; k < 4; k++) {
        po0[k] = pA[0][k] * liA0 + pA[1][k] * liA1 + pA[2][k] * liA2 + pA[3][k] * liA3
               + pB0[0][k] * liB0 + pB0[1][k] * liB1 + pB0[2][k] * liB2 + pB0[3][k] * liB3;
        po1[k] = pB1[0][k] * liB0 + pB1[1][k] * liB1 + pB1[2][k] * liB2 + pB1[3][k] * liB3;
    }
    *reinterpret_cast<float4*>(&Rpart[(long)bid * 2048 + c0]) = o0;
    *reinterpret_cast<float4*>(&Rpart[(long)bid * 2048 + 1024 + c0]) = o1;
}

// ---------------- K4: charge update T. 256 blocks; block = 32 cols x 8 partial-groups.
template <int T>
__global__ __launch_bounds__(256) void k_charge(const float* __restrict__ Rpart,
        const float* __restrict__ charge0, float4* __restrict__ charges4,
        const float* __restrict__ decayp) {
    __shared__ float s8[8][33];
    int g = threadIdx.x >> 5, cl = threadIdx.x & 31;
    int m = blockIdx.x * 32 + cl;           // global col id in [0,8192)
    int b = m >> 11, col = m & 2047;
    const float* rp = Rpart + ((long)(b * 256 + g * 32) * 2048) + col;
    float s = 0.f;
#pragma unroll
    for (int i = 0; i < 32; i++) s += rp[(long)i * 2048];
    s8[g][cl] = s;
    __syncthreads();
    if (threadIdx.x < 32) {
        float t = 0.f;
#pragma unroll
        for (int gg = 0; gg < 8; gg++) t += s8[gg][threadIdx.x];
        int mm = blockIdx.x * 32 + threadIdx.x;
        float decay = decayp[0];
        float prev = (T == 1) ? charge0[mm] : ((const float*)&charges4[mm])[T - 2];
        ((float*)&charges4[mm])[T - 1] = prev * (1.f - decay * sigm(t - 1.f));
    }
}

// ---------------- K5: final pass, single-pass PV with deferred normalization.
// 1024 blocks = 4 batches x 256 pairs {A rows [4p,4p+4), B rows [2044-4p,2048-4p)}.
// 8 live rows/block; MFMA A rows 8-15 fed from a zero LDS row (pbuf[8]).
// unroll 4 on MFMA loops keeps <=4 VbT loads in flight (full unroll spilled).
// pbuf row stride 1032 shorts = 2064 B = 129*16: 16B-aligned, odd-16B.
__global__ __launch_bounds__(256, 4) void k_stripPV(const ushort_t* __restrict__ compat,
        const float4* __restrict__ charges4, const float* __restrict__ stepp,
        const ushort_t* __restrict__ VbT, ushort_t* __restrict__ Abf) {
    __shared__ float chR[4][8], red[4][8], Li[8];
    __shared__ __align__(16) ushort_t pbuf[9][1032];
    int bid = blockIdx.x, tid = threadIdx.x;
    int b = bid >> 8, pi = bid & 255;
    int r0A = pi * 4, r0B = 2044 - pi * 4;
    float step = stepp[0];
    if (tid < 8) {
        int row = (tid < 4) ? (r0A + tid) : (r0B + tid - 4);
        float4 c4 = charges4[b * 2048 + row];
        chR[0][tid] = step * c4.x; chR[1][tid] = step * c4.y;
        chR[2][tid] = step * c4.z; chR[3][tid] = step * c4.w;
    }
    u16x4 zz = {0, 0, 0, 0};
    *reinterpret_cast<u16x4*>(&pbuf[8][tid * 4]) = zz;   // zero row for A-frag lanes 8-15
    __syncthreads();
    int w = tid >> 6, lane = tid & 63, l16 = lane & 15, quad = lane >> 4;
    int pr = (l16 < 8) ? l16 : 8;
    int c0 = tid * 4;
    const ushort_t* base = compat + (long)(b * 2048) * 2048;
    float S[8];
#pragma unroll
    for (int i = 0; i < 8; i++) S[i] = 0.f;
    f32x4 acc = {};

    // ---- chunk 0: cols [0,1024)
    {
        float cx[4], cy[4], cz[4], cw[4];
#pragma unroll
        for (int k = 0; k < 4; k++) {
            float4 c = charges4[b * 2048 + c0 + k];
            cx[k] = c.x; cy[k] = c.y; cz[k] = c.z; cw[k] = c.w;
        }
        if (c0 <= r0A + 3) {
#pragma unroll
            for (int i = 0; i < 4; i++) {
                u16x4 v = *reinterpret_cast<const u16x4*>(base + (long)(r0A + i) * 2048 + c0);
                u16x4 pv;
#pragma unroll
                for (int k = 0; k < 4; k++) {
                    float sg = 1.f + chR[0][i] * cx[k] + chR[1][i] * cy[k]
                                   + chR[2][i] * cz[k] + chR[3][i] * cw[k];
                    float p = (c0 + k <= r0A + i) ? __expf(bf2f(v[k]) * sg) : 0.f;
                    S[i] += p;
                    pv[k] = (ushort_t)f2bf(p);
                }
                *reinterpret_cast<u16x4*>(&pbuf[i][c0]) = pv;
            }
        } else {
#pragma unroll
            for (int i = 0; i < 4; i++) *reinterpret_cast<u16x4*>(&pbuf[i][c0]) = zz;
        }
#pragma unroll
        for (int i = 4; i < 8; i++) {
            u16x4 v = *reinterpret_cast<const u16x4*>(base + (long)(r0B + i - 4) * 2048 + c0);
            u16x4 pv;
#pragma unroll
            for (int k = 0; k < 4; k++) {
                float sg = 1.f + chR[0][i] * cx[k] + chR[1][i] * cy[k]
                               + chR[2][i] * cz[k] + chR[3][i] * cw[k];
                float p = __expf(bf2f(v[k]) * sg);   // col<1024 <= r0B always
                S[i] += p;
                pv[k] = (ushort_t)f2bf(p);
            }
            *reinterpret_cast<u16x4*>(&pbuf[i][c0]) = pv;
        }
    }
    __syncthreads();
#pragma unroll 4
    for (int k0 = 0; k0 < 1024; k0 += 32) {
        bf16x8 af = *reinterpret_cast<const bf16x8*>(&pbuf[pr][k0 + quad * 8]);
        bf16x8 vf = *reinterpret_cast<const bf16x8*>(
            VbT + (long)(w * 16 + l16) * 8192 + b * 2048 + k0 + quad * 8);
        acc = __builtin_amdgcn_mfma_f32_16x16x32_bf16(af, vf, acc, 0, 0, 0);
    }
    __syncthreads();
    // ---- chunk 1: cols [1024,2048): A rows zeroed; B rows masked (guarded)
    {
#pragma unroll
        for (int i = 0; i < 4; i++) *reinterpret_cast<u16x4*>(&pbuf[i][c0]) = zz;
        if (1024 + c0 <= r0B + 3) {
            float cx[4], cy[4], cz[4], cw[4];
#pragma unroll
            for (int k = 0; k < 4; k++) {
                float4 c = charges4[b * 2048 + 1024 + c0 + k];
                cx[k] = c.x; cy[k] = c.y; cz[k] = c.z; cw[k] = c.w;
            }
#pragma unroll
            for (int i = 4; i < 8; i++) {
                int grow = r0B + i - 4;
                u16x4 v = *reinterpret_cast<const u16x4*>(base + (long)grow * 2048 + 1024 + c0);
                u16x4 pv;
#pragma unroll
                for (int k = 0; k < 4; k++) {
                    float sg = 1.f + chR[0][i] * cx[k] + chR[1][i] * cy[k]
                                   + chR[2][i] * cz[k] + chR[3][i] * cw[k];
                    float p = (1024 + c0 + k <= grow) ? __expf(bf2f(v[k]) * sg) : 0.f;
                    S[i] += p;
                    pv[k] = (ushort_t)f2bf(p);
                }
                *reinterpret_cast<u16x4*>(&pbuf[i][c0]) = pv;
            }
        } else {
#pragma unroll
            for (int i = 4; i < 8; i++) *reinterpret_cast<u16x4*>(&pbuf[i][c0]) = zz;
        }
    }
    __syncthreads();
#pragma unroll 4
    for (int k0 = 0; k0 < 1024; k0 += 32) {
        bf16x8 af = *reinterpret_cast<const bf16x8*>(&pbuf[pr][k0 + quad * 8]);
        bf16x8 vf = *reinterpret_cast<const bf16x8*>(
            VbT + (long)(w * 16 + l16) * 8192 + b * 2048 + 1024 + k0 + quad * 8);
        acc = __builtin_amdgcn_mfma_f32_16x16x32_bf16(af, vf, acc, 0, 0, 0);
    }
    // ---- reduce S -> Li[8], scale acc, write rows 0-7
#pragma unroll
    for (int i = 0; i < 8; i++) {
        float s = S[i];
        s += __shfl_xor(s, 1); s += __shfl_xor(s, 2); s += __shfl_xor(s, 4);
        s += __shfl_xor(s, 8); s += __shfl_xor(s, 16); s += __shfl_xor(s, 32);
        if (lane == 0) red[w][i] = s;
    }
    __syncthreads();
    if (tid < 8) Li[tid] = 1.f / fmaxf(red[0][tid] + red[1][tid] + red[2][tid] + red[3][tid], 1e-30f);
    __syncthreads();
    if (quad < 2) {
#pragma unroll
        for (int rr = 0; rr < 4; rr++) {
            int row8 = quad * 4 + rr;   // 0..7
            int grow = (row8 < 4) ? (b * 2048 + r0A + row8) : (b * 2048 + r0B + row8 - 4);
            Abf[(long)grow * 64 + w * 16 + l16] = (ushort_t)f2bf(acc[rr] * Li[row8]);
        }
    }
}

// ---------------- K6: out = (Abf @ Wo^T) * 0.1, fp32 store
__global__ __launch_bounds__(256) void k_oproj(const ushort_t* __restrict__ Abf,
                                               const float* __restrict__ Wo,
                                               float* __restrict__ out) {
    int mt = blockIdx.x & 63, nt = blockIdx.x >> 6;
    int wave = threadIdx.x >> 6, lane = threadIdx.x & 63;
    int wm = wave >> 1, wn = wave & 1;
    int l16 = lane & 15, quad = lane >> 4;
    int row0 = mt * 128 + wm * 64;
    int col0 = nt * 128 + wn * 64;
    f32x4 acc[4][4] = {};
#pragma unroll
    for (int kc = 0; kc < 64; kc += 32) {
        int ko = kc + quad * 8;
        bf16x8 af[4], bfm[4];
#pragma unroll
        for (int f = 0; f < 4; f++)
            af[f] = *reinterpret_cast<const bf16x8*>(Abf + (long)(row0 + f * 16 + l16) * 64 + ko);
#pragma unroll
        for (int f = 0; f < 4; f++) bfm[f] = ld8f(Wo + (long)(col0 + f * 16 + l16) * 64 + ko);
#pragma unroll
        for (int i = 0; i < 4; i++)
#pragma unroll
            for (int j = 0; j < 4; j++)
                acc[i][j] = __builtin_amdgcn_mfma_f32_16x16x32_bf16(af[i], bfm[j], acc[i][j], 0, 0, 0);
    }
#pragma unroll
    for (int i = 0; i < 4; i++)
#pragma unroll
        for (int j = 0; j < 4; j++)
#pragma unroll
            for (int rr = 0; rr < 4; rr++) {
                long rowg = row0 + i * 16 + quad * 4 + rr;
                int colg = col0 + j * 16 + l16;
                out[rowg * 1024 + colg] = acc[i][j][rr] * 0.1f;
            }
}

extern "C" void kernel_launch(void* const* d_in, const int* in_sizes, int n_in,
                              void* d_out, int out_size, void* d_ws, size_t ws_size,
                              hipStream_t stream) {
    const float* hidden = (const float*)d_in[0];
    const float* W1 = (const float*)d_in[1];
    const float* b1 = (const float*)d_in[2];
    const float* W2 = (const float*)d_in[3];
    const float* b2 = (const float*)d_in[4];
    const float* Wq = (const float*)d_in[5];
    const float* Wk = (const float*)d_in[6];
    const float* Wc = (const float*)d_in[7];
    const float* bc = (const float*)d_in[8];
    const float* Wv = (const float*)d_in[9];
    const float* Wo = (const float*)d_in[10];
    const float* stepp = (const float*)d_in[11];
    const float* decayp = (const float*)d_in[12];

    char* ws = (char*)d_ws;
    size_t off = 0;
    auto alloc = [&](size_t bytes) {
        void* p = ws + off;
        off += (bytes + 255) & ~(size_t)255;
        return p;
    };
    ushort_t* compat = (ushort_t*)alloc(8192UL * 2048 * 2);   // 32 MiB bf16
    ushort_t* Wcat = (ushort_t*)alloc(128UL * 1024 * 2);      // W1;Wv bf16
    ushort_t* Qb = (ushort_t*)alloc(8192UL * 64 * 2);
    ushort_t* Kb = (ushort_t*)alloc(8192UL * 64 * 2);
    ushort_t* VbT = (ushort_t*)alloc(64UL * 8192 * 2);
    float* charge0 = (float*)alloc(8192UL * 4);
    float4* charges4 = (float4*)alloc(8192UL * 16);
    float* Rpart = (float*)alloc(1024UL * 2048 * 4);          // 8 MiB col partials
    ushort_t* Abf = (ushort_t*)alloc(8192UL * 64 * 2);        // 1 MiB normalized O
    (void)ws_size; (void)in_sizes; (void)n_in; (void)out_size;

    k_cvtW<<<64, 256, 0, stream>>>(W1, Wv, Wcat);
    k_fvfeat<<<1024, 256, 0, stream>>>(hidden, Wcat, b1, W2, b2, Wq, Wk, Wc, bc,
                                       Qb, Kb, VbT, charge0);
    k_compat<<<1088, 256, 0, stream>>>(Qb, Kb, compat);

    k_strip<0><<<1024, 256, 0, stream>>>(compat, charges4, stepp, Rpart);
    k_charge<1><<<256, 256, 0, stream>>>(Rpart, charge0, charges4, decayp);
    k_strip<1><<<1024, 256, 0, stream>>>(compat, charges4, stepp, Rpart);
    k_charge<2><<<256, 256, 0, stream>>>(Rpart, charge0, charges4, decayp);
    k_strip<2><<<1024, 256, 0, stream>>>(compat, charges4, stepp, Rpart);
    k_charge<3><<<256, 256, 0, stream>>>(Rpart, charge0, charges4, decayp);
    k_strip<3><<<1024, 256, 0, stream>>>(compat, charges4, stepp, Rpart);
    k_charge<4><<<256, 256, 0, stream>>>(Rpart, charge0, charges4, decayp);

    k_stripPV<<<1024, 256, 0, stream>>>(compat, charges4, stepp, VbT, Abf);
    k_oproj<<<512, 256, 0, stream>>>(Abf, Wo, (float*)d_out);
}

// Round 12
// 254.839 us; speedup vs baseline: 1.0894x; 1.0894x over previous
//
#include <hip/hip_runtime.h>
#include <hip/hip_bf16.h>

typedef unsigned short ushort_t;
typedef short bf16x8 __attribute__((ext_vector_type(8)));
typedef ushort_t u16x8 __attribute__((ext_vector_type(8)));
typedef ushort_t u16x4 __attribute__((ext_vector_type(4)));
typedef float f32x4 __attribute__((ext_vector_type(4)));

#define DEV static __device__ __forceinline__

DEV float bf2f(ushort_t u) { unsigned v = ((unsigned)u) << 16; float f; __builtin_memcpy(&f, &v, 4); return f; }
DEV short f2bf(float x) { __hip_bfloat16 h = __float2bfloat16(x); short s; __builtin_memcpy(&s, &h, 2); return s; }
DEV float sigm(float x) { return 1.0f / (1.0f + __expf(-x)); }

DEV bf16x8 cvt8(float4 a0, float4 a1) {
    bf16x8 t;
    t[0] = f2bf(a0.x); t[1] = f2bf(a0.y); t[2] = f2bf(a0.z); t[3] = f2bf(a0.w);
    t[4] = f2bf(a1.x); t[5] = f2bf(a1.y); t[6] = f2bf(a1.z); t[7] = f2bf(a1.w);
    return t;
}
DEV bf16x8 ld8f(const float* __restrict__ p) {
    return cvt8(*reinterpret_cast<const float4*>(p), *reinterpret_cast<const float4*>(p + 4));
}

// ---------------- K0: fp32 -> bf16 for W1, Wv only
__global__ void k_cvtW(const float* __restrict__ W1, const float* __restrict__ Wv,
                       ushort_t* __restrict__ Wcat) {
    int i = blockIdx.x * 256 + threadIdx.x;  // 16384 threads, 8 elems each
    const float* src = (i < 8192) ? (W1 + (long)i * 8) : (Wv + (long)(i - 8192) * 8);
    const float4* p = reinterpret_cast<const float4*>(src);
    *reinterpret_cast<bf16x8*>(Wcat + (long)i * 8) = cvt8(p[0], p[1]);
}

// ---------------- K1: fused fv+feat, LDS-staged hidden + K-split waves. 512 blocks.
// Phase 0: cooperative stage of 16 hidden rows -> bf16 hLDS (independent loads, BW-bound).
//          [round-11 NaN bug was here: row = f>>6 instead of f>>8 -> LDS OOB]
// Phase 1: wave (khalf=w>>1, tg=w&1) computes 4 output tiles over its K-half from
//          hLDS (A) and L2-resident Wcat (B): 4 independent MFMA chains of 16.
// Phase 2: partial[2][8][16][16] LDS reduce -> gelu/fLDS (t<4) or VbT (t>=4).
// Phase 3: feat chain (sigmoid(f@W2^T) -> Q,K,charge0) unchanged.
__global__ __launch_bounds__(256) void k_fvfeat(const float* __restrict__ hidden,
        const ushort_t* __restrict__ Wcat, const float* __restrict__ b1,
        const float* __restrict__ W2, const float* __restrict__ b2,
        const float* __restrict__ Wq, const float* __restrict__ Wk,
        const float* __restrict__ Wc, const float* __restrict__ bc,
        ushort_t* __restrict__ Qb, ushort_t* __restrict__ Kb,
        ushort_t* __restrict__ VbT, float* __restrict__ charge0) {
    __shared__ float w2L[28 * 65], wqL[64 * 29], wkL[64 * 29], wcL[28], b2L[28];
    __shared__ float fLDS[16][65], featL[4][28];
    __shared__ __align__(16) ushort_t hLDS[16][1032];  // stride 2064B: 16B-mult, odd-16B
    __shared__ float part[2][8][16][16];
    int tid = threadIdx.x;
    int m0 = blockIdx.x * 16;
    for (int i = tid; i < 28 * 64; i += 256) w2L[(i >> 6) * 65 + (i & 63)] = W2[i];
    for (int i = tid; i < 64 * 28; i += 256) {
        int r = i / 28, c = i - r * 28;
        wqL[r * 29 + c] = Wq[i];
        wkL[r * 29 + c] = Wk[i];
    }
    if (tid < 28) { wcL[tid] = Wc[tid]; b2L[tid] = b2[tid]; }
    // ---- stage hidden rows [m0, m0+16) as bf16 into LDS (4096 float4s; 256 f4/row)
    {
        const float4* hp = reinterpret_cast<const float4*>(hidden + (long)m0 * 1024);
#pragma unroll 4
        for (int it = 0; it < 16; it++) {
            int f = it * 256 + tid;
            int row = f >> 8, colf = f & 255;   // FIXED: 256 float4s per 1024-col row
            float4 v = hp[f];
            u16x4 o;
            o[0] = (ushort_t)f2bf(v.x); o[1] = (ushort_t)f2bf(v.y);
            o[2] = (ushort_t)f2bf(v.z); o[3] = (ushort_t)f2bf(v.w);
            *reinterpret_cast<u16x4*>(&hLDS[row][colf * 4]) = o;
        }
    }
    __syncthreads();
    int wave = tid >> 6, lane = tid & 63, l16 = lane & 15, quad = lane >> 4;
    int khalf = wave >> 1, tg = wave & 1;
    f32x4 acc[4] = {};
    const ushort_t* bbase = Wcat + (long)(tg * 64 + l16) * 1024;
    {
        int kbase = khalf * 512;
#pragma unroll 2
        for (int s = 0; s < 16; s++) {
            int ko = kbase + s * 32 + quad * 8;
            bf16x8 a = *reinterpret_cast<const bf16x8*>(&hLDS[l16][ko]);
#pragma unroll
            for (int i = 0; i < 4; i++) {
                bf16x8 bfr = *reinterpret_cast<const bf16x8*>(bbase + (long)i * 16384 + ko);
                acc[i] = __builtin_amdgcn_mfma_f32_16x16x32_bf16(a, bfr, acc[i], 0, 0, 0);
            }
        }
    }
#pragma unroll
    for (int i = 0; i < 4; i++)
#pragma unroll
        for (int rr = 0; rr < 4; rr++)
            part[khalf][tg * 4 + i][quad * 4 + rr][l16] = acc[i][rr];
    __syncthreads();
    // ---- combine partials: 2048 outputs, 8 per thread
    {
        int t = tid >> 5, r = (tid >> 1) & 15, ch = tid & 1;
        const float4 a0 = *reinterpret_cast<const float4*>(&part[0][t][r][ch * 8]);
        const float4 a1 = *reinterpret_cast<const float4*>(&part[0][t][r][ch * 8 + 4]);
        const float4 c0v = *reinterpret_cast<const float4*>(&part[1][t][r][ch * 8]);
        const float4 c1v = *reinterpret_cast<const float4*>(&part[1][t][r][ch * 8 + 4]);
        float v[8] = {a0.x + c0v.x, a0.y + c0v.y, a0.z + c0v.z, a0.w + c0v.w,
                      a1.x + c1v.x, a1.y + c1v.y, a1.z + c1v.z, a1.w + c1v.w};
        int colbase = t * 16 + ch * 8;
        if (t < 4) {
#pragma unroll
            for (int j = 0; j < 8; j++) {
                float x = v[j] + b1[colbase + j];
                fLDS[r][colbase + j] = 0.5f * x * (1.0f + erff(x * 0.70710678118654752f));
            }
        } else {
#pragma unroll
            for (int j = 0; j < 8; j++)
                VbT[(long)(colbase + j - 64) * 8192 + m0 + r] = (ushort_t)f2bf(v[j]);
        }
    }
    __syncthreads();
    // ---- feat chain
    float bcv = bc[0];
    for (int it = 0; it < 4; it++) {
        int rowl = it * 4 + wave;
        int row = m0 + rowl;
        if (lane < 28) {
            float s = b2L[lane];
#pragma unroll
            for (int j = 0; j < 64; j++) s += fLDS[rowl][j] * w2L[lane * 65 + j];
            featL[wave][lane] = sigm(s);
        }
        __syncthreads();
        float q = 0.f, k = 0.f;
#pragma unroll
        for (int i = 0; i < 28; i++) {
            float fv = featL[wave][i];
            q += fv * wqL[lane * 29 + i];
            k += fv * wkL[lane * 29 + i];
        }
        Qb[row * 64 + lane] = (ushort_t)f2bf(q * 0.125f);  // fold 1/sqrt(64)
        Kb[row * 64 + lane] = (ushort_t)f2bf(k);
        if (lane == 0) {
            float c = bcv;
#pragma unroll
            for (int i = 0; i < 28; i++) c += featL[wave][i] * wcL[i];
            charge0[row] = sigm(c);
        }
        __syncthreads();
    }
}

DEV void tri_decode(int r, int& ti, int& tj) {
    int t = (int)((sqrtf(8.f * (float)r + 1.f) - 1.f) * 0.5f);
    while ((t + 1) * (t + 2) / 2 <= r) t++;
    while (t * (t + 1) / 2 > r) t--;
    ti = t;
    tj = r - t * (t + 1) / 2;
}

// ---------------- K2: compat = (Q/8)·K, causal 128x128 tiles, bf16
__global__ __launch_bounds__(256) void k_compat(const ushort_t* __restrict__ Qb,
                                                const ushort_t* __restrict__ Kb,
                                                ushort_t* __restrict__ compat) {
    int bid = blockIdx.x;
    int b = bid / 136, r = bid % 136, ti, tj;
    tri_decode(r, ti, tj);
    int wave = threadIdx.x >> 6, lane = threadIdx.x & 63;
    int l16 = lane & 15, quad = lane >> 4;
    int rbase = b * 2048 + ti * 128 + wave * 32;
    int cbase = b * 2048 + tj * 128;
    f32x4 acc[2][8] = {};
#pragma unroll
    for (int kc = 0; kc < 64; kc += 32) {
        int ko = kc + quad * 8;
        bf16x8 af[2], bf[8];
#pragma unroll
        for (int f = 0; f < 2; f++)
            af[f] = *reinterpret_cast<const bf16x8*>(Qb + (long)(rbase + f * 16 + l16) * 64 + ko);
#pragma unroll
        for (int f = 0; f < 8; f++)
            bf[f] = *reinterpret_cast<const bf16x8*>(Kb + (long)(cbase + f * 16 + l16) * 64 + ko);
#pragma unroll
        for (int i = 0; i < 2; i++)
#pragma unroll
            for (int j = 0; j < 8; j++)
                acc[i][j] = __builtin_amdgcn_mfma_f32_16x16x32_bf16(af[i], bf[j], acc[i][j], 0, 0, 0);
    }
    int colt = tj * 128;
#pragma unroll
    for (int i = 0; i < 2; i++)
#pragma unroll
        for (int j = 0; j < 8; j++)
#pragma unroll
            for (int rr = 0; rr < 4; rr++) {
                long rowg = rbase + i * 16 + quad * 4 + rr;
                int col = colt + j * 16 + l16;
                compat[rowg * 2048 + col] = (ushort_t)f2bf(acc[i][j][rr]);
            }
}

// ---------------- K3: single-pass strip kernel, iteration T.
// 1024 blocks = 4 batches x 256 pairs {A rows [4p,4p+4), B rows [2044-4p,2048-4p)}.
// Block-uniform guards skip fully-masked spans; zero-init arrays keep partials exact.
template <int T>
__global__ __launch_bounds__(256, 2) void k_strip(const ushort_t* __restrict__ compat,
        const float4* __restrict__ charges4, const float* __restrict__ stepp,
        float* __restrict__ Rpart) {
    __shared__ float chR[4][8];   // [comp][row: 0-3 A, 4-7 B]
    __shared__ float red[4][8], Li[8];
    int bid = blockIdx.x, tid = threadIdx.x;
    int b = bid >> 8, pi = bid & 255;
    int r0A = pi * 4, r0B = 2044 - pi * 4;
    float step = stepp[0];
    if (T > 0 && tid < 8) {
        int row = (tid < 4) ? (r0A + tid) : (r0B + tid - 4);
        float4 c4 = charges4[b * 2048 + row];
        chR[0][tid] = step * c4.x;
        if (T > 1) chR[1][tid] = step * c4.y;
        if (T > 2) chR[2][tid] = step * c4.z;
        if (T > 3) chR[3][tid] = step * c4.w;
    }
    __syncthreads();
    int w = tid >> 6, lane = tid & 63;
    int c0 = tid * 4;
    const ushort_t* base = compat + (long)(b * 2048) * 2048;

    float pA[4][4] = {}, pB0[4][4] = {}, pB1[4][4] = {};
    float SA[4] = {}, SB[4] = {};

    // ---- chunk 0: cols [c0, c0+4) in [0,1024)
    {
        float cx[4] = {}, cy[4] = {}, cz[4] = {}, cw[4] = {};
        if (T > 0) {
#pragma unroll
            for (int k = 0; k < 4; k++) {
                float4 c = charges4[b * 2048 + c0 + k];
                cx[k] = c.x;
                if (T > 1) cy[k] = c.y;
                if (T > 2) cz[k] = c.z;
                if (T > 3) cw[k] = c.w;
            }
        }
        if (c0 <= r0A + 3) {   // skip fully-masked A spans
#pragma unroll
            for (int rr = 0; rr < 4; rr++) {
                u16x4 v = *reinterpret_cast<const u16x4*>(base + (long)(r0A + rr) * 2048 + c0);
#pragma unroll
                for (int k = 0; k < 4; k++) {
                    float sg = 1.f;
                    if (T > 0) sg += chR[0][rr] * cx[k];
                    if (T > 1) sg += chR[1][rr] * cy[k];
                    if (T > 2) sg += chR[2][rr] * cz[k];
                    if (T > 3) sg += chR[3][rr] * cw[k];
                    float p = (c0 + k <= r0A + rr) ? __expf(bf2f(v[k]) * sg) : 0.f;
                    pA[rr][k] = p;
                    SA[rr] += p;
                }
            }
        }
#pragma unroll
        for (int rr = 0; rr < 4; rr++) {
            u16x4 v = *reinterpret_cast<const u16x4*>(base + (long)(r0B + rr) * 2048 + c0);
#pragma unroll
            for (int k = 0; k < 4; k++) {
                float sg = 1.f;
                if (T > 0) sg += chR[0][4 + rr] * cx[k];
                if (T > 1) sg += chR[1][4 + rr] * cy[k];
                if (T > 2) sg += chR[2][4 + rr] * cz[k];
                if (T > 3) sg += chR[3][4 + rr] * cw[k];
                float p = __expf(bf2f(v[k]) * sg);   // col<1024 <= r0B always
                pB0[rr][k] = p;
                SB[rr] += p;
            }
        }
    }
    // ---- chunk 1: cols 1024+[c0, c0+4), B rows only (masked, guarded)
    if (1024 + c0 <= r0B + 3) {
        float cx[4] = {}, cy[4] = {}, cz[4] = {}, cw[4] = {};
        if (T > 0) {
#pragma unroll
            for (int k = 0; k < 4; k++) {
                float4 c = charges4[b * 2048 + 1024 + c0 + k];
                cx[k] = c.x;
                if (T > 1) cy[k] = c.y;
                if (T > 2) cz[k] = c.z;
                if (T > 3) cw[k] = c.w;
            }
        }
#pragma unroll
        for (int rr = 0; rr < 4; rr++) {
            u16x4 v = *reinterpret_cast<const u16x4*>(base + (long)(r0B + rr) * 2048 + 1024 + c0);
#pragma unroll
            for (int k = 0; k < 4; k++) {
                float sg = 1.f;
                if (T > 0) sg += chR[0][4 + rr] * cx[k];
                if (T > 1) sg += chR[1][4 + rr] * cy[k];
                if (T > 2) sg += chR[2][4 + rr] * cz[k];
                if (T > 3) sg += chR[3][4 + rr] * cw[k];
                float p = (1024 + c0 + k <= r0B + rr) ? __expf(bf2f(v[k]) * sg) : 0.f;
                pB1[rr][k] = p;
                SB[rr] += p;
            }
        }
    }
    // ---- reduce row sums -> Li[8]
#pragma unroll
    for (int rr = 0; rr < 4; rr++) {
        float s = SA[rr];
        s += __shfl_xor(s, 1); s += __shfl_xor(s, 2); s += __shfl_xor(s, 4);
        s += __shfl_xor(s, 8); s += __shfl_xor(s, 16); s += __shfl_xor(s, 32);
        if (lane == 0) red[w][rr] = s;
        float t = SB[rr];
        t += __shfl_xor(t, 1); t += __shfl_xor(t, 2); t += __shfl_xor(t, 4);
        t += __shfl_xor(t, 8); t += __shfl_xor(t, 16); t += __shfl_xor(t, 32);
        if (lane == 0) red[w][4 + rr] = t;
    }
    __syncthreads();
    if (tid < 8) Li[tid] = 1.f / fmaxf(red[0][tid] + red[1][tid] + red[2][tid] + red[3][tid], 1e-30f);
    __syncthreads();
    float liA0 = Li[0], liA1 = Li[1], liA2 = Li[2], liA3 = Li[3];
    float liB0 = Li[4], liB1 = Li[5], liB2 = Li[6], liB3 = Li[7];
    float4 o0, o1;
    float* po0 = (float*)&o0;
    float* po1 = (float*)&o1;
#pragma unroll
    for (int k = 0; k < 4; k++) {
        po0[k] = pA[0][k] * liA0 + pA[1][k] * liA1 + pA[2][k] * liA2 + pA[3][k] * liA3
               + pB0[0][k] * liB0 + pB0[1][k] * liB1 + pB0[2][k] * liB2 + pB0[3][k] * liB3;
        po1[k] = pB1[0][k] * liB0 + pB1[1][k] * liB1 + pB1[2][k] * liB2 + pB1[3][k] * liB3;
    }
    *reinterpret_cast<float4*>(&Rpart[(long)bid * 2048 + c0]) = o0;
    *reinterpret_cast<float4*>(&Rpart[(long)bid * 2048 + 1024 + c0]) = o1;
}

// ---------------- K4: charge update T. 256 blocks; block = 32 cols x 8 partial-groups.
template <int T>
__global__ __launch_bounds__(256) void k_charge(const float* __restrict__ Rpart,
        const float* __restrict__ charge0, float4* __restrict__ charges4,
        const float* __restrict__ decayp) {
    __shared__ float s8[8][33];
    int g = threadIdx.x >> 5, cl = threadIdx.x & 31;
    int m = blockIdx.x * 32 + cl;           // global col id in [0,8192)
    int b = m >> 11, col = m & 2047;
    const float* rp = Rpart + ((long)(b * 256 + g * 32) * 2048) + col;
    float s = 0.f;
#pragma unroll
    for (int i = 0; i < 32; i++) s += rp[(long)i * 2048];
    s8[g][cl] = s;
    __syncthreads();
    if (threadIdx.x < 32) {
        float t = 0.f;
#pragma unroll
        for (int gg = 0; gg < 8; gg++) t += s8[gg][threadIdx.x];
        int mm = blockIdx.x * 32 + threadIdx.x;
        float decay = decayp[0];
        float prev = (T == 1) ? charge0[mm] : ((const float*)&charges4[mm])[T - 2];
        ((float*)&charges4[mm])[T - 1] = prev * (1.f - decay * sigm(t - 1.f));
    }
}

// ---------------- K5: final pass, single-pass PV with deferred normalization.
// 1024 blocks = 4 batches x 256 pairs {A rows [4p,4p+4), B rows [2044-4p,2048-4p)}.
// 8 live rows/block; MFMA A rows 8-15 fed from a zero LDS row (pbuf[8]).
// unroll 4 on MFMA loops keeps <=4 VbT loads in flight (full unroll spilled).
// pbuf row stride 1032 shorts = 2064 B = 129*16: 16B-aligned, odd-16B.
__global__ __launch_bounds__(256, 4) void k_stripPV(const ushort_t* __restrict__ compat,
        const float4* __restrict__ charges4, const float* __restrict__ stepp,
        const ushort_t* __restrict__ VbT, ushort_t* __restrict__ Abf) {
    __shared__ float chR[4][8], red[4][8], Li[8];
    __shared__ __align__(16) ushort_t pbuf[9][1032];
    int bid = blockIdx.x, tid = threadIdx.x;
    int b = bid >> 8, pi = bid & 255;
    int r0A = pi * 4, r0B = 2044 - pi * 4;
    float step = stepp[0];
    if (tid < 8) {
        int row = (tid < 4) ? (r0A + tid) : (r0B + tid - 4);
        float4 c4 = charges4[b * 2048 + row];
        chR[0][tid] = step * c4.x; chR[1][tid] = step * c4.y;
        chR[2][tid] = step * c4.z; chR[3][tid] = step * c4.w;
    }
    u16x4 zz = {0, 0, 0, 0};
    *reinterpret_cast<u16x4*>(&pbuf[8][tid * 4]) = zz;   // zero row for A-frag lanes 8-15
    __syncthreads();
    int w = tid >> 6, lane = tid & 63, l16 = lane & 15, quad = lane >> 4;
    int pr = (l16 < 8) ? l16 : 8;
    int c0 = tid * 4;
    const ushort_t* base = compat + (long)(b * 2048) * 2048;
    float S[8];
#pragma unroll
    for (int i = 0; i < 8; i++) S[i] = 0.f;
    f32x4 acc = {};

    // ---- chunk 0: cols [0,1024)
    {
        float cx[4], cy[4], cz[4], cw[4];
#pragma unroll
        for (int k = 0; k < 4; k++) {
            float4 c = charges4[b * 2048 + c0 + k];
            cx[k] = c.x; cy[k] = c.y; cz[k] = c.z; cw[k] = c.w;
        }
        if (c0 <= r0A + 3) {
#pragma unroll
            for (int i = 0; i < 4; i++) {
                u16x4 v = *reinterpret_cast<const u16x4*>(base + (long)(r0A + i) * 2048 + c0);
                u16x4 pv;
#pragma unroll
                for (int k = 0; k < 4; k++) {
                    float sg = 1.f + chR[0][i] * cx[k] + chR[1][i] * cy[k]
                                   + chR[2][i] * cz[k] + chR[3][i] * cw[k];
                    float p = (c0 + k <= r0A + i) ? __expf(bf2f(v[k]) * sg) : 0.f;
                    S[i] += p;
                    pv[k] = (ushort_t)f2bf(p);
                }
                *reinterpret_cast<u16x4*>(&pbuf[i][c0]) = pv;
            }
        } else {
#pragma unroll
            for (int i = 0; i < 4; i++) *reinterpret_cast<u16x4*>(&pbuf[i][c0]) = zz;
        }
#pragma unroll
        for (int i = 4; i < 8; i++) {
            u16x4 v = *reinterpret_cast<const u16x4*>(base + (long)(r0B + i - 4) * 2048 + c0);
            u16x4 pv;
#pragma unroll
            for (int k = 0; k < 4; k++) {
                float sg = 1.f + chR[0][i] * cx[k] + chR[1][i] * cy[k]
                               + chR[2][i] * cz[k] + chR[3][i] * cw[k];
                float p = __expf(bf2f(v[k]) * sg);   // col<1024 <= r0B always
                S[i] += p;
                pv[k] = (ushort_t)f2bf(p);
            }
            *reinterpret_cast<u16x4*>(&pbuf[i][c0]) = pv;
        }
    }
    __syncthreads();
#pragma unroll 4
    for (int k0 = 0; k0 < 1024; k0 += 32) {
        bf16x8 af = *reinterpret_cast<const bf16x8*>(&pbuf[pr][k0 + quad * 8]);
        bf16x8 vf = *reinterpret_cast<const bf16x8*>(
            VbT + (long)(w * 16 + l16) * 8192 + b * 2048 + k0 + quad * 8);
        acc = __builtin_amdgcn_mfma_f32_16x16x32_bf16(af, vf, acc, 0, 0, 0);
    }
    __syncthreads();
    // ---- chunk 1: cols [1024,2048): A rows zeroed; B rows masked (guarded)
    {
#pragma unroll
        for (int i = 0; i < 4; i++) *reinterpret_cast<u16x4*>(&pbuf[i][c0]) = zz;
        if (1024 + c0 <= r0B + 3) {
            float cx[4], cy[4], cz[4], cw[4];
#pragma unroll
            for (int k = 0; k < 4; k++) {
                float4 c = charges4[b * 2048 + 1024 + c0 + k];
                cx[k] = c.x; cy[k] = c.y; cz[k] = c.z; cw[k] = c.w;
            }
#pragma unroll
            for (int i = 4; i < 8; i++) {
                int grow = r0B + i - 4;
                u16x4 v = *reinterpret_cast<const u16x4*>(base + (long)grow * 2048 + 1024 + c0);
                u16x4 pv;
#pragma unroll
                for (int k = 0; k < 4; k++) {
                    float sg = 1.f + chR[0][i] * cx[k] + chR[1][i] * cy[k]
                                   + chR[2][i] * cz[k] + chR[3][i] * cw[k];
                    float p = (1024 + c0 + k <= grow) ? __expf(bf2f(v[k]) * sg) : 0.f;
                    S[i] += p;
                    pv[k] = (ushort_t)f2bf(p);
                }
                *reinterpret_cast<u16x4*>(&pbuf[i][c0]) = pv;
            }
        } else {
#pragma unroll
            for (int i = 4; i < 8; i++) *reinterpret_cast<u16x4*>(&pbuf[i][c0]) = zz;
        }
    }
    __syncthreads();
#pragma unroll 4
    for (int k0 = 0; k0 < 1024; k0 += 32) {
        bf16x8 af = *reinterpret_cast<const bf16x8*>(&pbuf[pr][k0 + quad * 8]);
        bf16x8 vf = *reinterpret_cast<const bf16x8*>(
            VbT + (long)(w * 16 + l16) * 8192 + b * 2048 + 1024 + k0 + quad * 8);
        acc = __builtin_amdgcn_mfma_f32_16x16x32_bf16(af, vf, acc, 0, 0, 0);
    }
    // ---- reduce S -> Li[8], scale acc, write rows 0-7
#pragma unroll
    for (int i = 0; i < 8; i++) {
        float s = S[i];
        s += __shfl_xor(s, 1); s += __shfl_xor(s, 2); s += __shfl_xor(s, 4);
        s += __shfl_xor(s, 8); s += __shfl_xor(s, 16); s += __shfl_xor(s, 32);
        if (lane == 0) red[w][i] = s;
    }
    __syncthreads();
    if (tid < 8) Li[tid] = 1.f / fmaxf(red[0][tid] + red[1][tid] + red[2][tid] + red[3][tid], 1e-30f);
    __syncthreads();
    if (quad < 2) {
#pragma unroll
        for (int rr = 0; rr < 4; rr++) {
            int row8 = quad * 4 + rr;   // 0..7
            int grow = (row8 < 4) ? (b * 2048 + r0A + row8) : (b * 2048 + r0B + row8 - 4);
            Abf[(long)grow * 64 + w * 16 + l16] = (ushort_t)f2bf(acc[rr] * Li[row8]);
        }
    }
}

// ---------------- K6: out = (Abf @ Wo^T) * 0.1, fp32 store
__global__ __launch_bounds__(256) void k_oproj(const ushort_t* __restrict__ Abf,
                                               const float* __restrict__ Wo,
                                               float* __restrict__ out) {
    int mt = blockIdx.x & 63, nt = blockIdx.x >> 6;
    int wave = threadIdx.x >> 6, lane = threadIdx.x & 63;
    int wm = wave >> 1, wn = wave & 1;
    int l16 = lane & 15, quad = lane >> 4;
    int row0 = mt * 128 + wm * 64;
    int col0 = nt * 128 + wn * 64;
    f32x4 acc[4][4] = {};
#pragma unroll
    for (int kc = 0; kc < 64; kc += 32) {
        int ko = kc + quad * 8;
        bf16x8 af[4], bfm[4];
#pragma unroll
        for (int f = 0; f < 4; f++)
            af[f] = *reinterpret_cast<const bf16x8*>(Abf + (long)(row0 + f * 16 + l16) * 64 + ko);
#pragma unroll
        for (int f = 0; f < 4; f++) bfm[f] = ld8f(Wo + (long)(col0 + f * 16 + l16) * 64 + ko);
#pragma unroll
        for (int i = 0; i < 4; i++)
#pragma unroll
            for (int j = 0; j < 4; j++)
                acc[i][j] = __builtin_amdgcn_mfma_f32_16x16x32_bf16(af[i], bfm[j], acc[i][j], 0, 0, 0);
    }
#pragma unroll
    for (int i = 0; i < 4; i++)
#pragma unroll
        for (int j = 0; j < 4; j++)
#pragma unroll
            for (int rr = 0; rr < 4; rr++) {
                long rowg = row0 + i * 16 + quad * 4 + rr;
                int colg = col0 + j * 16 + l16;
                out[rowg * 1024 + colg] = acc[i][j][rr] * 0.1f;
            }
}

extern "C" void kernel_launch(void* const* d_in, const int* in_sizes, int n_in,
                              void* d_out, int out_size, void* d_ws, size_t ws_size,
                              hipStream_t stream) {
    const float* hidden = (const float*)d_in[0];
    const float* W1 = (const float*)d_in[1];
    const float* b1 = (const float*)d_in[2];
    const float* W2 = (const float*)d_in[3];
    const float* b2 = (const float*)d_in[4];
    const float* Wq = (const float*)d_in[5];
    const float* Wk = (const float*)d_in[6];
    const float* Wc = (const float*)d_in[7];
    const float* bc = (const float*)d_in[8];
    const float* Wv = (const float*)d_in[9];
    const float* Wo = (const float*)d_in[10];
    const float* stepp = (const float*)d_in[11];
    const float* decayp = (const float*)d_in[12];

    char* ws = (char*)d_ws;
    size_t off = 0;
    auto alloc = [&](size_t bytes) {
        void* p = ws + off;
        off += (bytes + 255) & ~(size_t)255;
        return p;
    };
    ushort_t* compat = (ushort_t*)alloc(8192UL * 2048 * 2);   // 32 MiB bf16
    ushort_t* Wcat = (ushort_t*)alloc(128UL * 1024 * 2);      // W1;Wv bf16
    ushort_t* Qb = (ushort_t*)alloc(8192UL * 64 * 2);
    ushort_t* Kb = (ushort_t*)alloc(8192UL * 64 * 2);
    ushort_t* VbT = (ushort_t*)alloc(64UL * 8192 * 2);
    float* charge0 = (float*)alloc(8192UL * 4);
    float4* charges4 = (float4*)alloc(8192UL * 16);
    float* Rpart = (float*)alloc(1024UL * 2048 * 4);          // 8 MiB col partials
    ushort_t* Abf = (ushort_t*)alloc(8192UL * 64 * 2);        // 1 MiB normalized O
    (void)ws_size; (void)in_sizes; (void)n_in; (void)out_size;

    k_cvtW<<<64, 256, 0, stream>>>(W1, Wv, Wcat);
    k_fvfeat<<<512, 256, 0, stream>>>(hidden, Wcat, b1, W2, b2, Wq, Wk, Wc, bc,
                                      Qb, Kb, VbT, charge0);
    k_compat<<<544, 256, 0, stream>>>(Qb, Kb, compat);

    k_strip<0><<<1024, 256, 0, stream>>>(compat, charges4, stepp, Rpart);
    k_charge<1><<<256, 256, 0, stream>>>(Rpart, charge0, charges4, decayp);
    k_strip<1><<<1024, 256, 0, stream>>>(compat, charges4, stepp, Rpart);
    k_charge<2><<<256, 256, 0, stream>>>(Rpart, charge0, charges4, decayp);
    k_strip<2><<<1024, 256, 0, stream>>>(compat, charges4, stepp, Rpart);
    k_charge<3><<<256, 256, 0, stream>>>(Rpart, charge0, charges4, decayp);
    k_strip<3><<<1024, 256, 0, stream>>>(compat, charges4, stepp, Rpart);
    k_charge<4><<<256, 256, 0, stream>>>(Rpart, charge0, charges4, decayp);

    k_stripPV<<<1024, 256, 0, stream>>>(compat, charges4, stepp, VbT, Abf);
    k_oproj<<<512, 256, 0, stream>>>(Abf, Wo, (float*)d_out);
}